// Round 1
// baseline (5507.340 us; speedup 1.0000x reference)
//
#include <hip/hip_runtime.h>
#include <hip/hip_bf16.h>

// ActivePerceptionLayer: B=8192, IN=512, D=256, F=64, A=128, H=8, HD=16, BUDGET=16
//
// Pipeline:
//  K0: fuse M = op_w @ out_proj_w [512,128], b' = op_b + op_w @ out_proj_b
//  K1: per-row MLPs (uncertainty / feat_imp / samp_probs), top-16 selection,
//      writes 5 small outputs + feature-grouped row lists (atomic counting sort)
//  K2: grouped by feature: enc = af[f,rows] @ enc_w[f]^T + b ; qkv = enc @ W_in^T + b
//      -> qkv_sel [B,16,384] bf16 (only the 16 selected features per row)
//  K3: collapsed attention: 48 masked positions share qkv = in_proj_b, so
//      17x17 scores per (row,head); outputs mean_ctx [B,128] (mean over seq folded in)
//  K4: enhanced_x = x + mean_ctx @ M^T + b'
//
// Workspace (~102.3 MB): qkv bf16 100663296 | mean_ctx 4 MB | M 256KB | b' 2KB
//                        | rows_by_f 2 MB | counts 256 B

#define NB 8192

// ---------------- K0: fold out_proj and output_projection ----------------
__global__ __launch_bounds__(256) void k0_fuse(
    const float* __restrict__ op_w, const float* __restrict__ out_proj_w,
    const float* __restrict__ out_proj_b, const float* __restrict__ op_b,
    float* __restrict__ M, float* __restrict__ bf)
{
  int g = blockIdx.x;
  if (g < 256) {
    int t = g * 256 + threadIdx.x;       // 0..65535
    int i = t >> 7, j = t & 127;         // M[i][j] = sum_k op_w[i][k]*out_proj_w[k][j]
    float acc = 0.f;
    for (int k = 0; k < 128; k++) acc += op_w[i * 128 + k] * out_proj_w[k * 128 + j];
    M[i * 128 + j] = acc;
  } else {
    for (int ii = threadIdx.x; ii < 512; ii += 256) {
      float acc = op_b[ii];
      for (int k = 0; k < 128; k++) acc += op_w[ii * 128 + k] * out_proj_b[k];
      bf[ii] = acc;
    }
  }
}

// ---------------- K1 helpers ----------------
// h1[16][129] = relu( xs[16rows][K] @ w1[128][K]^T + b1 )   (256 threads)
__device__ __forceinline__ void mlp_h1(const float* __restrict__ w1,
                                       const float* __restrict__ b1, int K,
                                       const float (*xs)[576], float (*wt)[33],
                                       float (*h1)[129], int t)
{
  const int i = t & 127, rg = t >> 7;      // output dim, row group (8 rows each)
  const int il = t >> 1, kb = (t & 1) * 16; // load mapping
  float acc[8];
#pragma unroll
  for (int rr = 0; rr < 8; rr++) acc[rr] = 0.f;
  for (int kc = 0; kc < K; kc += 32) {
    __syncthreads();
    const float* wr = w1 + (size_t)il * K + kc + kb;
#pragma unroll
    for (int q = 0; q < 16; q++) wt[il][kb + q] = wr[q];
    __syncthreads();
#pragma unroll
    for (int kk = 0; kk < 32; kk++) {
      float w = wt[i][kk];
#pragma unroll
      for (int rr = 0; rr < 8; rr++)
        acc[rr] += w * xs[rg * 8 + rr][kc + kk];
    }
  }
  float bv = b1[i];
#pragma unroll
  for (int rr = 0; rr < 8; rr++) {
    float v = acc[rr] + bv;
    h1[rg * 8 + rr][i] = v > 0.f ? v : 0.f;
  }
}

// fl[16][64] = h1[16][128] @ w2[64][128]^T + b2   (raw logits; 256 threads)
// wt2 aliases the low 64 rows of wt_raw; fl lives above them (no overlap).
__device__ __forceinline__ void mlp_out64(const float* __restrict__ w2,
                                          const float* __restrict__ b2,
                                          const float (*h1)[129], float (*wt2)[33],
                                          float (*fl)[64], int t)
{
  const int o = t & 63, rg4 = t >> 6;      // output, row group (4 rows each)
  const int ol = t >> 2, kb = (t & 3) * 8;
  float acc[4];
#pragma unroll
  for (int rr = 0; rr < 4; rr++) acc[rr] = 0.f;
  for (int kc = 0; kc < 128; kc += 32) {
    __syncthreads();
    const float* wr = w2 + ol * 128 + kc + kb;
#pragma unroll
    for (int q = 0; q < 8; q++) wt2[ol][kb + q] = wr[q];
    __syncthreads();
#pragma unroll
    for (int kk = 0; kk < 32; kk++) {
      float w = wt2[o][kk];
#pragma unroll
      for (int rr = 0; rr < 4; rr++)
        acc[rr] += w * h1[rg4 * 4 + rr][kc + kk];
    }
  }
  float bv = b2[o];
#pragma unroll
  for (int rr = 0; rr < 4; rr++) fl[rg4 * 4 + rr][o] = acc[rr] + bv;
}

// ---------------- K1: MLPs + softmax + top-k + grouping ----------------
__global__ __launch_bounds__(256) void k1_mlp(
    const float* __restrict__ x, const float* __restrict__ costs,
    const float* __restrict__ ue_w1, const float* __restrict__ ue_b1,
    const float* __restrict__ ue_w2, const float* __restrict__ ue_b2,
    const float* __restrict__ fi_w1, const float* __restrict__ fi_b1,
    const float* __restrict__ fi_w2, const float* __restrict__ fi_b2,
    const float* __restrict__ sd_w1, const float* __restrict__ sd_b1,
    const float* __restrict__ sd_w2, const float* __restrict__ sd_b2,
    float* __restrict__ out_unc, float* __restrict__ out_fi,
    float* __restrict__ out_sp, float* __restrict__ out_mask,
    float* __restrict__ out_cost, int* __restrict__ rows_by_f,
    int* __restrict__ counts)
{
  __shared__ float xs[16][576];        // x(512) ++ feat_imp(64)
  __shared__ float wt_raw[128 * 33];   // weight tiles; fl aliases upper part
  __shared__ float h1[16][129];        // +1 pad: conflict-free column reads
  __shared__ float uu[16];
  float (*wt)[33] = (float(*)[33])wt_raw;
  float (*fl)[64] = (float(*)[64])(wt_raw + 64 * 33);  // 1024 floats, fits
  const int t = threadIdx.x;
  const int b0 = blockIdx.x * 16;

  { // stage x into LDS
    int r = t >> 4, c0 = (t & 15) * 32;
    const float* xr = x + (size_t)(b0 + r) * 512 + c0;
#pragma unroll
    for (int q = 0; q < 32; q++) xs[r][c0 + q] = xr[q];
  }
  // --- uncertainty ---
  mlp_h1(ue_w1, ue_b1, 512, xs, wt, h1, t);
  __syncthreads();
  if (t < 16) {
    float a = ue_b2[0];
    for (int k = 0; k < 128; k++) a += ue_w2[k] * h1[t][k];
    float u = 1.f / (1.f + expf(-a));
    uu[t] = u;
    out_unc[b0 + t] = u;
  }
  __syncthreads();
  // --- feature importance ---
  mlp_h1(fi_w1, fi_b1, 512, xs, wt, h1, t);
  __syncthreads();
  mlp_out64(fi_w2, fi_b2, h1, wt, fl, t);
  __syncthreads();
  const int lane = t & 63, wv = t >> 6;
  for (int p = 0; p < 4; p++) {     // softmax over F=64, one wave per row
    int r = p * 4 + wv;
    float v = fl[r][lane];
    float m = v;
    for (int off = 32; off; off >>= 1) m = fmaxf(m, __shfl_xor(m, off));
    float e = expf(v - m);
    float s = e;
    for (int off = 32; off; off >>= 1) s += __shfl_xor(s, off);
    float fv = e / s;
    xs[r][512 + lane] = fv;         // concat for sampling_decision input
    out_fi[(size_t)(b0 + r) * 64 + lane] = fv;
  }
  __syncthreads();
  // --- sampling decision ---
  mlp_h1(sd_w1, sd_b1, 576, xs, wt, h1, t);
  __syncthreads();
  mlp_out64(sd_w2, sd_b2, h1, wt, fl, t);
  __syncthreads();
  float cst = costs[lane];
  for (int p = 0; p < 4; p++) {
    int r = p * 4 + wv;
    float lg = fl[r][lane];
    float pr = 1.f / (1.f + expf(-lg));
    out_sp[(size_t)(b0 + r) * 64 + lane] = pr;
    fl[r][lane] = pr / (1.f + cst) * uu[r];   // adjusted score
  }
  __syncthreads();
  // --- top-16 per row (iterative wave argmax, ties -> lower index like jax) ---
  for (int p = 0; p < 4; p++) {
    int r = p * 4 + wv;
    float a = fl[r][lane];
    float msk = 0.f;
    for (int it = 0; it < 16; it++) {
      float bv = a;
      int bi = lane;
      for (int off = 32; off; off >>= 1) {
        float ov = __shfl_xor(bv, off);
        int oi = __shfl_xor(bi, off);
        if (ov > bv || (ov == bv && oi < bi)) { bv = ov; bi = oi; }
      }
      if (lane == bi) {
        msk = 1.f;
        a = -__builtin_inff();
        int slot = atomicAdd(&counts[bi], 1);           // counting sort by feature
        rows_by_f[bi * NB + slot] = ((b0 + r) << 4) | it; // pack (row, j-slot)
      }
    }
    out_mask[(size_t)(b0 + r) * 64 + lane] = msk;
    float mc = msk * cst;
    for (int off = 32; off; off >>= 1) mc += __shfl_xor(mc, off);
    if (lane == 0) out_cost[b0 + r] = mc;
  }
}

// ---------------- K2: grouped encoder + qkv projection ----------------
__global__ __launch_bounds__(256) void k2_enc(
    const float* __restrict__ af, const float* __restrict__ enc_w,
    const float* __restrict__ enc_b, const float* __restrict__ ipw,
    const float* __restrict__ ipb, const int* __restrict__ rows_by_f,
    const int* __restrict__ counts, __hip_bfloat16* __restrict__ qkv_sel)
{
  __shared__ float afb[16][256];
  __shared__ float wt[128][65];   // +1 pad
  __shared__ float eo[16][128];
  __shared__ int ent[16];
  const int f = blockIdx.x;
  const int cnt = counts[f];
  const int base = blockIdx.y * 16;
  if (base >= cnt) return;
  const int t = threadIdx.x;
  const int nr = min(16, cnt - base);
  if (t < 16) ent[t] = (t < nr) ? rows_by_f[f * NB + base + t] : -1;
  __syncthreads();
  { // gather 16 rows of available_features[f]
    int r = t >> 4, c0 = (t & 15) * 16;
    int e = ent[r];
    if (e >= 0) {
      const float* src = af + ((size_t)f * NB + (e >> 4)) * 256 + c0;
#pragma unroll
      for (int q = 0; q < 16; q++) afb[r][c0 + q] = src[q];
    } else {
#pragma unroll
      for (int q = 0; q < 16; q++) afb[r][c0 + q] = 0.f;
    }
  }
  const int i = t & 127, rg = t >> 7;
  const int il = t >> 1, kb = (t & 1) * 32;
  // enc = afb @ enc_w[f]^T + enc_b[f]   (K=256)
  float acc[8];
#pragma unroll
  for (int rr = 0; rr < 8; rr++) acc[rr] = 0.f;
  const float* wf = enc_w + (size_t)f * 128 * 256;
  for (int kc = 0; kc < 256; kc += 64) {
    __syncthreads();
    const float* wr = wf + il * 256 + kc + kb;
#pragma unroll
    for (int q = 0; q < 32; q++) wt[il][kb + q] = wr[q];
    __syncthreads();
#pragma unroll
    for (int kk = 0; kk < 64; kk++) {
      float w = wt[i][kk];
#pragma unroll
      for (int rr = 0; rr < 8; rr++) acc[rr] += w * afb[rg * 8 + rr][kc + kk];
    }
  }
  float bv = enc_b[f * 128 + i];
#pragma unroll
  for (int rr = 0; rr < 8; rr++) eo[rg * 8 + rr][i] = acc[rr] + bv;
  // qkv = eo @ ipw^T + ipb   (out 384 in 3 chunks, K=128 in 2 chunks)
  for (int oc = 0; oc < 3; oc++) {
    float a2[8];
#pragma unroll
    for (int rr = 0; rr < 8; rr++) a2[rr] = 0.f;
    for (int kc = 0; kc < 128; kc += 64) {
      __syncthreads();
      const float* wr = ipw + (oc * 128 + il) * 128 + kc + kb;
#pragma unroll
      for (int q = 0; q < 32; q++) wt[il][kb + q] = wr[q];
      __syncthreads();
#pragma unroll
      for (int kk = 0; kk < 64; kk++) {
        float w = wt[i][kk];
#pragma unroll
        for (int rr = 0; rr < 8; rr++) a2[rr] += w * eo[rg * 8 + rr][kc + kk];
      }
    }
    float b2 = ipb[oc * 128 + i];
#pragma unroll
    for (int rr = 0; rr < 8; rr++) {
      int e = ent[rg * 8 + rr];
      if (e >= 0) {
        size_t bb = (size_t)(e >> 4), j = (size_t)(e & 15);
        qkv_sel[(bb * 16 + j) * 384 + oc * 128 + i] = __float2bfloat16(a2[rr] + b2);
      }
    }
  }
}

// ---------------- K3: collapsed attention -> mean_ctx [B,128] ----------------
__global__ __launch_bounds__(192) void k3_attn(
    const __hip_bfloat16* __restrict__ qkv_sel, const float* __restrict__ ipb,
    float* __restrict__ mean_ctx)
{
  __shared__ float qt[384][17];     // transposed: qt[channel][pos], pos 16 = bias
  __shared__ float sm[8][17][18];
  __shared__ float cw[8][18];
  const int b = blockIdx.x, t = threadIdx.x;
  const __hip_bfloat16* src = qkv_sel + (size_t)b * 16 * 384;
  for (int j = 0; j < 16; j++)
    for (int c = t; c < 384; c += 192)
      qt[c][j] = __bfloat162float(src[j * 384 + c]);
  for (int c = t; c < 384; c += 192) qt[c][16] = ipb[c];   // masked-position qkv
  __syncthreads();
  if (t < 136) {                     // scores: (h, qi) worker
    int h = t / 17, qi = t % 17;
    const int qb = h * 16, kbx = 128 + h * 16;
    float qv[16];
#pragma unroll
    for (int d = 0; d < 16; d++) qv[d] = qt[qb + d][qi];
    for (int ki = 0; ki < 17; ki++) {
      float s = 0.f;
#pragma unroll
      for (int d = 0; d < 16; d++) s += qv[d] * qt[kbx + d][ki];
      sm[h][qi][ki] = s * 0.25f;     // 1/sqrt(HD=16)
    }
  }
  __syncthreads();
  if (t < 136) {                     // softmax per (h, qi); 48 copies of bias key
    int h = t / 17, qi = t % 17;
    float m = -__builtin_inff();
    for (int ki = 0; ki < 17; ki++) m = fmaxf(m, sm[h][qi][ki]);
    float e[17], den = 0.f;
#pragma unroll
    for (int ki = 0; ki < 17; ki++) {
      e[ki] = expf(sm[h][qi][ki] - m);
      den += (ki == 16 ? 48.f : 1.f) * e[ki];
    }
    float mult = (qi == 16) ? 48.f : 1.f;  // 48 masked query rows are identical
    float inv = mult / den;
#pragma unroll
    for (int ki = 0; ki < 17; ki++) sm[h][qi][ki] = e[ki] * inv;
  }
  __syncthreads();
  if (t < 136) {                     // combined key weight over all queries
    int h = t / 17, ki = t % 17;
    float s = 0.f;
    for (int qi = 0; qi < 17; qi++) s += sm[h][qi][ki];
    cw[h][ki] = s * ((ki == 16) ? 48.f : 1.f) * (1.f / 64.f);  // mean over F
  }
  __syncthreads();
  if (t < 128) {                     // mean_ctx[h*16+d] = sum_ki cw * v
    int h = t >> 4, d = t & 15;
    int vb = 256 + h * 16 + d;
    float s = 0.f;
#pragma unroll
    for (int ki = 0; ki < 17; ki++) s += cw[h][ki] * qt[vb][ki];
    mean_ctx[(size_t)b * 128 + t] = s;
  }
}

// ---------------- K4: enhanced_x = x + mean_ctx @ M^T + b' ----------------
__global__ __launch_bounds__(256) void k4_out(
    const float* __restrict__ x, const float* __restrict__ mc,
    const float* __restrict__ M, const float* __restrict__ bf,
    float* __restrict__ out)
{
  __shared__ float ms[32][128];
  __shared__ float wt[128][65];
  const int t = threadIdx.x;
  const int b0 = blockIdx.x * 32;
  {
    int r = t >> 3, c0 = (t & 7) * 16;
    const float* s = mc + (size_t)(b0 + r) * 128 + c0;
#pragma unroll
    for (int q = 0; q < 16; q++) ms[r][c0 + q] = s[q];
  }
  const int i = t & 127, rg = t >> 7;   // 16 rows per thread
  const int il = t >> 1, kb = (t & 1) * 32;
  for (int oc = 0; oc < 4; oc++) {
    float acc[16];
#pragma unroll
    for (int rr = 0; rr < 16; rr++) acc[rr] = 0.f;
    for (int kc = 0; kc < 128; kc += 64) {
      __syncthreads();
      const float* wr = M + (oc * 128 + il) * 128 + kc + kb;
#pragma unroll
      for (int q = 0; q < 32; q++) wt[il][kb + q] = wr[q];
      __syncthreads();
#pragma unroll
      for (int kk = 0; kk < 64; kk++) {
        float w = wt[i][kk];
#pragma unroll
        for (int rr = 0; rr < 16; rr++) acc[rr] += w * ms[rg * 16 + rr][kc + kk];
      }
    }
    float bb = bf[oc * 128 + i];
#pragma unroll
    for (int rr = 0; rr < 16; rr++) {
      size_t idx = (size_t)(b0 + rg * 16 + rr) * 512 + oc * 128 + i;
      out[idx] = x[idx] + acc[rr] + bb;
    }
  }
}

// ---------------- host ----------------
extern "C" void kernel_launch(void* const* d_in, const int* in_sizes, int n_in,
                              void* d_out, int out_size, void* d_ws, size_t ws_size,
                              hipStream_t stream)
{
  const float* x      = (const float*)d_in[0];
  const float* af     = (const float*)d_in[1];
  const float* costs  = (const float*)d_in[2];
  const float* ue_w1  = (const float*)d_in[3];
  const float* ue_b1  = (const float*)d_in[4];
  const float* ue_w2  = (const float*)d_in[5];
  const float* ue_b2  = (const float*)d_in[6];
  const float* fi_w1  = (const float*)d_in[7];
  const float* fi_b1  = (const float*)d_in[8];
  const float* fi_w2  = (const float*)d_in[9];
  const float* fi_b2  = (const float*)d_in[10];
  const float* sd_w1  = (const float*)d_in[11];
  const float* sd_b1  = (const float*)d_in[12];
  const float* sd_w2  = (const float*)d_in[13];
  const float* sd_b2  = (const float*)d_in[14];
  const float* enc_w  = (const float*)d_in[15];
  const float* enc_b  = (const float*)d_in[16];
  const float* ipw    = (const float*)d_in[17];
  const float* ipb    = (const float*)d_in[18];
  const float* opjw   = (const float*)d_in[19];
  const float* opjb   = (const float*)d_in[20];
  const float* op_w   = (const float*)d_in[21];
  const float* op_b   = (const float*)d_in[22];

  float* out = (float*)d_out;
  float* out_enh  = out;                    // [B,512]
  float* out_unc  = out + 4194304;          // [B,1]
  float* out_fi   = out_unc + 8192;         // [B,64]
  float* out_sp   = out_fi + 524288;        // [B,64]
  float* out_mask = out_sp + 524288;        // [B,64]
  float* out_cost = out_mask + 524288;      // [B]

  char* ws = (char*)d_ws;
  __hip_bfloat16* qkv = (__hip_bfloat16*)ws;          // 100,663,296 B
  float* mc     = (float*)(ws + 100663296);           // 4 MB
  float* M      = (float*)(ws + 104857600);           // 256 KB
  float* bfv    = (float*)(ws + 105119744);           // 2 KB
  int*   rows   = (int*)  (ws + 105121792);           // 2 MB
  int*   counts = (int*)  (ws + 107218944);           // 256 B

  hipMemsetAsync(counts, 0, 64 * sizeof(int), stream);
  k0_fuse<<<257, 256, 0, stream>>>(op_w, opjw, opjb, op_b, M, bfv);
  k1_mlp<<<512, 256, 0, stream>>>(x, costs, ue_w1, ue_b1, ue_w2, ue_b2,
                                  fi_w1, fi_b1, fi_w2, fi_b2,
                                  sd_w1, sd_b1, sd_w2, sd_b2,
                                  out_unc, out_fi, out_sp, out_mask, out_cost,
                                  rows, counts);
  k2_enc<<<dim3(64, 512), 256, 0, stream>>>(af, enc_w, enc_b, ipw, ipb,
                                            rows, counts, qkv);
  k3_attn<<<8192, 192, 0, stream>>>(qkv, ipb, mc);
  k4_out<<<256, 256, 0, stream>>>(x, mc, M, bfv, out_enh);
}

// Round 2
// 2284.925 us; speedup vs baseline: 2.4103x; 2.4103x over previous
//
#include <hip/hip_runtime.h>
#include <hip/hip_bf16.h>

// ActivePerceptionLayer: B=8192, IN=512, D=256, F=64, A=128, H=8, HD=16, BUDGET=16
//
// Pipeline:
//  K0 : fuse M = op_w @ out_proj_w [512,128], b' = op_b + op_w @ out_proj_b
//  K0b: convert enc_w + in_proj_w to bf16 (weights re-read by 4096 K2 blocks)
//  K1 : per-row MLPs (uncertainty / feat_imp / samp_probs) fp32, top-16 select,
//       writes 5 small outputs + feature-grouped row lists (atomic counting sort)
//  K2 : MFMA per feature-group: 32 rows/block;
//       GEMM1 enc[32x128] = af_rows[32x256] @ enc_w[f]^T  (bf16 MFMA, fp32 acc)
//       GEMM2 qkv[32x384] = enc @ in_proj_w^T              -> qkv_sel bf16
//       A-operands via padded LDS; B-operands straight from L2 (bf16 weights)
//  K3 : collapsed attention (48 masked positions share qkv=in_proj_b -> 17x17)
//       -> mean_ctx [B,128] (mean over seq folded in)
//  K4 : enhanced_x = x + mean_ctx @ M^T + b'
//
// Workspace (~107.3 MB): qkv bf16 | enc_w_bf 4MB (aliased by mean_ctx after K2)
//                        | ipw_bf | M | b' | rows_by_f | counts

#define NB 8192

typedef __attribute__((ext_vector_type(8))) short short8;
typedef __attribute__((ext_vector_type(4))) float f32x4;

// ---------------- K0: fold out_proj and output_projection ----------------
__global__ __launch_bounds__(256) void k0_fuse(
    const float* __restrict__ op_w, const float* __restrict__ out_proj_w,
    const float* __restrict__ out_proj_b, const float* __restrict__ op_b,
    float* __restrict__ M, float* __restrict__ bf)
{
  int g = blockIdx.x;
  if (g < 256) {
    int t = g * 256 + threadIdx.x;       // 0..65535
    int i = t >> 7, j = t & 127;         // M[i][j] = sum_k op_w[i][k]*out_proj_w[k][j]
    float acc = 0.f;
    for (int k = 0; k < 128; k++) acc += op_w[i * 128 + k] * out_proj_w[k * 128 + j];
    M[i * 128 + j] = acc;
  } else {
    for (int ii = threadIdx.x; ii < 512; ii += 256) {
      float acc = op_b[ii];
      for (int k = 0; k < 128; k++) acc += op_w[ii * 128 + k] * out_proj_b[k];
      bf[ii] = acc;
    }
  }
}

// ---------------- K0b: fp32 -> bf16 weight conversion ----------------
__global__ __launch_bounds__(256) void k0b_cvt(
    const float* __restrict__ encw, const float* __restrict__ ipw,
    __hip_bfloat16* __restrict__ encw_bf, __hip_bfloat16* __restrict__ ipw_bf)
{
  const int NE = 64 * 128 * 256;            // 2,097,152 (mult of 4)
  const int NT4 = (NE + 384 * 128) / 4;     // 536,576 groups of 4
  int i4 = blockIdx.x * 256 + threadIdx.x;
  if (i4 >= NT4) return;
  int i = i4 * 4;
  float4 v = (i < NE) ? *(const float4*)(encw + i)
                      : *(const float4*)(ipw + (i - NE));
  union { __hip_bfloat16 h[4]; short4 s; } u;
  u.h[0] = __float2bfloat16(v.x); u.h[1] = __float2bfloat16(v.y);
  u.h[2] = __float2bfloat16(v.z); u.h[3] = __float2bfloat16(v.w);
  if (i < NE) *(short4*)(encw_bf + i) = u.s;
  else        *(short4*)(ipw_bf + (i - NE)) = u.s;
}

// ---------------- K1 helpers ----------------
__device__ __forceinline__ void mlp_h1(const float* __restrict__ w1,
                                       const float* __restrict__ b1, int K,
                                       const float (*xs)[576], float (*wt)[33],
                                       float (*h1)[129], int t)
{
  const int i = t & 127, rg = t >> 7;
  const int il = t >> 1, kb = (t & 1) * 16;
  float acc[8];
#pragma unroll
  for (int rr = 0; rr < 8; rr++) acc[rr] = 0.f;
  for (int kc = 0; kc < K; kc += 32) {
    __syncthreads();
    const float* wr = w1 + (size_t)il * K + kc + kb;
#pragma unroll
    for (int q = 0; q < 16; q++) wt[il][kb + q] = wr[q];
    __syncthreads();
#pragma unroll
    for (int kk = 0; kk < 32; kk++) {
      float w = wt[i][kk];
#pragma unroll
      for (int rr = 0; rr < 8; rr++)
        acc[rr] += w * xs[rg * 8 + rr][kc + kk];
    }
  }
  float bv = b1[i];
#pragma unroll
  for (int rr = 0; rr < 8; rr++) {
    float v = acc[rr] + bv;
    h1[rg * 8 + rr][i] = v > 0.f ? v : 0.f;
  }
}

__device__ __forceinline__ void mlp_out64(const float* __restrict__ w2,
                                          const float* __restrict__ b2,
                                          const float (*h1)[129], float (*wt2)[33],
                                          float (*fl)[64], int t)
{
  const int o = t & 63, rg4 = t >> 6;
  const int ol = t >> 2, kb = (t & 3) * 8;
  float acc[4];
#pragma unroll
  for (int rr = 0; rr < 4; rr++) acc[rr] = 0.f;
  for (int kc = 0; kc < 128; kc += 32) {
    __syncthreads();
    const float* wr = w2 + ol * 128 + kc + kb;
#pragma unroll
    for (int q = 0; q < 8; q++) wt2[ol][kb + q] = wr[q];
    __syncthreads();
#pragma unroll
    for (int kk = 0; kk < 32; kk++) {
      float w = wt2[o][kk];
#pragma unroll
      for (int rr = 0; rr < 4; rr++)
        acc[rr] += w * h1[rg4 * 4 + rr][kc + kk];
    }
  }
  float bv = b2[o];
#pragma unroll
  for (int rr = 0; rr < 4; rr++) fl[rg4 * 4 + rr][o] = acc[rr] + bv;
}

// ---------------- K1: MLPs + softmax + top-k + grouping ----------------
__global__ __launch_bounds__(256) void k1_mlp(
    const float* __restrict__ x, const float* __restrict__ costs,
    const float* __restrict__ ue_w1, const float* __restrict__ ue_b1,
    const float* __restrict__ ue_w2, const float* __restrict__ ue_b2,
    const float* __restrict__ fi_w1, const float* __restrict__ fi_b1,
    const float* __restrict__ fi_w2, const float* __restrict__ fi_b2,
    const float* __restrict__ sd_w1, const float* __restrict__ sd_b1,
    const float* __restrict__ sd_w2, const float* __restrict__ sd_b2,
    float* __restrict__ out_unc, float* __restrict__ out_fi,
    float* __restrict__ out_sp, float* __restrict__ out_mask,
    float* __restrict__ out_cost, int* __restrict__ rows_by_f,
    int* __restrict__ counts)
{
  __shared__ float xs[16][576];
  __shared__ float wt_raw[128 * 33];
  __shared__ float h1[16][129];
  __shared__ float uu[16];
  float (*wt)[33] = (float(*)[33])wt_raw;
  float (*fl)[64] = (float(*)[64])(wt_raw + 64 * 33);
  const int t = threadIdx.x;
  const int b0 = blockIdx.x * 16;

  {
    int r = t >> 4, c0 = (t & 15) * 32;
    const float* xr = x + (size_t)(b0 + r) * 512 + c0;
#pragma unroll
    for (int q = 0; q < 32; q++) xs[r][c0 + q] = xr[q];
  }
  mlp_h1(ue_w1, ue_b1, 512, xs, wt, h1, t);
  __syncthreads();
  if (t < 16) {
    float a = ue_b2[0];
    for (int k = 0; k < 128; k++) a += ue_w2[k] * h1[t][k];
    float u = 1.f / (1.f + expf(-a));
    uu[t] = u;
    out_unc[b0 + t] = u;
  }
  __syncthreads();
  mlp_h1(fi_w1, fi_b1, 512, xs, wt, h1, t);
  __syncthreads();
  mlp_out64(fi_w2, fi_b2, h1, wt, fl, t);
  __syncthreads();
  const int lane = t & 63, wv = t >> 6;
  for (int p = 0; p < 4; p++) {
    int r = p * 4 + wv;
    float v = fl[r][lane];
    float m = v;
    for (int off = 32; off; off >>= 1) m = fmaxf(m, __shfl_xor(m, off));
    float e = expf(v - m);
    float s = e;
    for (int off = 32; off; off >>= 1) s += __shfl_xor(s, off);
    float fv = e / s;
    xs[r][512 + lane] = fv;
    out_fi[(size_t)(b0 + r) * 64 + lane] = fv;
  }
  __syncthreads();
  mlp_h1(sd_w1, sd_b1, 576, xs, wt, h1, t);
  __syncthreads();
  mlp_out64(sd_w2, sd_b2, h1, wt, fl, t);
  __syncthreads();
  float cst = costs[lane];
  for (int p = 0; p < 4; p++) {
    int r = p * 4 + wv;
    float lg = fl[r][lane];
    float pr = 1.f / (1.f + expf(-lg));
    out_sp[(size_t)(b0 + r) * 64 + lane] = pr;
    fl[r][lane] = pr / (1.f + cst) * uu[r];
  }
  __syncthreads();
  for (int p = 0; p < 4; p++) {
    int r = p * 4 + wv;
    float a = fl[r][lane];
    float msk = 0.f;
    for (int it = 0; it < 16; it++) {
      float bv = a;
      int bi = lane;
      for (int off = 32; off; off >>= 1) {
        float ov = __shfl_xor(bv, off);
        int oi = __shfl_xor(bi, off);
        if (ov > bv || (ov == bv && oi < bi)) { bv = ov; bi = oi; }
      }
      if (lane == bi) {
        msk = 1.f;
        a = -__builtin_inff();
        int slot = atomicAdd(&counts[bi], 1);
        rows_by_f[bi * NB + slot] = ((b0 + r) << 4) | it;
      }
    }
    out_mask[(size_t)(b0 + r) * 64 + lane] = msk;
    float mc = msk * cst;
    for (int off = 32; off; off >>= 1) mc += __shfl_xor(mc, off);
    if (lane == 0) out_cost[b0 + r] = mc;
  }
}

// ---------------- K2: MFMA grouped encoder + qkv projection ----------------
// 32 rows per block, 4 waves. A-operands from padded LDS, B-operands from L2.
__global__ __launch_bounds__(256) void k2_mfma(
    const float* __restrict__ af, const __hip_bfloat16* __restrict__ encw_bf,
    const float* __restrict__ enc_b, const __hip_bfloat16* __restrict__ ipw_bf,
    const float* __restrict__ ipb, const int* __restrict__ rows_by_f,
    const int* __restrict__ counts, __hip_bfloat16* __restrict__ qkv)
{
  __shared__ __align__(16) __hip_bfloat16 af_lds[32][264];   // +8 pad: no bank alias
  __shared__ __align__(16) __hip_bfloat16 enc_lds[32][136];  // +8 pad
  __shared__ int ent[32];
  const int f = blockIdx.x;
  const int cnt = counts[f];
  const int base = blockIdx.y * 32;
  if (base >= cnt) return;
  const int t = threadIdx.x;
  const int nr = min(32, cnt - base);
  if (t < 32) ent[t] = (t < nr) ? rows_by_f[f * NB + base + t] : -1;
  __syncthreads();
  { // gather 32 rows of available_features[f], convert fp32->bf16
    int r = t >> 3, c0 = (t & 7) * 32;
    int e = ent[r];
    if (e >= 0) {
      const float* src = af + ((size_t)f * NB + (size_t)(e >> 4)) * 256 + c0;
#pragma unroll
      for (int q = 0; q < 8; q++) {
        float4 v = *(const float4*)(src + q * 4);
        union { __hip_bfloat16 h[4]; short4 s; } u;
        u.h[0] = __float2bfloat16(v.x); u.h[1] = __float2bfloat16(v.y);
        u.h[2] = __float2bfloat16(v.z); u.h[3] = __float2bfloat16(v.w);
        *(short4*)&af_lds[r][c0 + q * 4] = u.s;
      }
    } else {
      short4 z = {0, 0, 0, 0};
#pragma unroll
      for (int q = 0; q < 8; q++) *(short4*)&af_lds[r][c0 + q * 4] = z;
    }
  }
  __syncthreads();
  const int lane = t & 63, wv = t >> 6;
  const int lr = lane & 15, quad = lane >> 4;
  const int r0 = (wv & 1) * 16;          // row half
  // ---- GEMM1: enc[32x128] = af[32x256] @ enc_w[f][128x256]^T ----
  const __hip_bfloat16* wf = encw_bf + (size_t)f * 32768;
  const int c0 = (wv >> 1) * 64;         // col half (4 tiles of 16)
  f32x4 acc[4];
#pragma unroll
  for (int ct = 0; ct < 4; ct++) acc[ct] = (f32x4){0.f, 0.f, 0.f, 0.f};
#pragma unroll
  for (int ks = 0; ks < 8; ks++) {
    short8 a = *(const short8*)&af_lds[r0 + lr][ks * 32 + quad * 8];
#pragma unroll
    for (int ct = 0; ct < 4; ct++) {
      short8 b = *(const short8*)(wf + (size_t)(c0 + ct * 16 + lr) * 256 + ks * 32 + quad * 8);
      acc[ct] = __builtin_amdgcn_mfma_f32_16x16x32_bf16(a, b, acc[ct], 0, 0, 0);
    }
  }
#pragma unroll
  for (int ct = 0; ct < 4; ct++) {
    int col = c0 + ct * 16 + lr;
    float bv = enc_b[f * 128 + col];
#pragma unroll
    for (int rr = 0; rr < 4; rr++)
      enc_lds[r0 + quad * 4 + rr][col] = __float2bfloat16(acc[ct][rr] + bv);
  }
  __syncthreads();
  // ---- GEMM2: qkv[32x384] = enc[32x128] @ in_proj_w[384x128]^T ----
  short8 a2[4];
#pragma unroll
  for (int ks = 0; ks < 4; ks++)
    a2[ks] = *(const short8*)&enc_lds[r0 + lr][ks * 32 + quad * 8];
  const int o0 = (wv >> 1) * 192;        // 12 tiles of 16
#pragma unroll
  for (int ot = 0; ot < 12; ot++) {
    int ob = o0 + ot * 16;
    f32x4 c2 = (f32x4){0.f, 0.f, 0.f, 0.f};
#pragma unroll
    for (int ks = 0; ks < 4; ks++) {
      short8 b = *(const short8*)(ipw_bf + (size_t)(ob + lr) * 128 + ks * 32 + quad * 8);
      c2 = __builtin_amdgcn_mfma_f32_16x16x32_bf16(a2[ks], b, c2, 0, 0, 0);
    }
    int col = ob + lr;
    float bv = ipb[col];
#pragma unroll
    for (int rr = 0; rr < 4; rr++) {
      int e = ent[r0 + quad * 4 + rr];
      if (e >= 0)
        qkv[((size_t)(e >> 4) * 16 + (size_t)(e & 15)) * 384 + col] =
            __float2bfloat16(c2[rr] + bv);
    }
  }
}

// ---------------- K3: collapsed attention -> mean_ctx [B,128] ----------------
__global__ __launch_bounds__(192) void k3_attn(
    const __hip_bfloat16* __restrict__ qkv_sel, const float* __restrict__ ipb,
    float* __restrict__ mean_ctx)
{
  __shared__ float qt[384][17];
  __shared__ float sm[8][17][18];
  __shared__ float cw[8][18];
  const int b = blockIdx.x, t = threadIdx.x;
  const __hip_bfloat16* src = qkv_sel + (size_t)b * 16 * 384;
  for (int j = 0; j < 16; j++)
    for (int c = t; c < 384; c += 192)
      qt[c][j] = __bfloat162float(src[j * 384 + c]);
  for (int c = t; c < 384; c += 192) qt[c][16] = ipb[c];
  __syncthreads();
  if (t < 136) {
    int h = t / 17, qi = t % 17;
    const int qb = h * 16, kbx = 128 + h * 16;
    float qv[16];
#pragma unroll
    for (int d = 0; d < 16; d++) qv[d] = qt[qb + d][qi];
    for (int ki = 0; ki < 17; ki++) {
      float s = 0.f;
#pragma unroll
      for (int d = 0; d < 16; d++) s += qv[d] * qt[kbx + d][ki];
      sm[h][qi][ki] = s * 0.25f;
    }
  }
  __syncthreads();
  if (t < 136) {
    int h = t / 17, qi = t % 17;
    float m = -__builtin_inff();
    for (int ki = 0; ki < 17; ki++) m = fmaxf(m, sm[h][qi][ki]);
    float e[17], den = 0.f;
#pragma unroll
    for (int ki = 0; ki < 17; ki++) {
      e[ki] = expf(sm[h][qi][ki] - m);
      den += (ki == 16 ? 48.f : 1.f) * e[ki];
    }
    float mult = (qi == 16) ? 48.f : 1.f;
    float inv = mult / den;
#pragma unroll
    for (int ki = 0; ki < 17; ki++) sm[h][qi][ki] = e[ki] * inv;
  }
  __syncthreads();
  if (t < 136) {
    int h = t / 17, ki = t % 17;
    float s = 0.f;
    for (int qi = 0; qi < 17; qi++) s += sm[h][qi][ki];
    cw[h][ki] = s * ((ki == 16) ? 48.f : 1.f) * (1.f / 64.f);
  }
  __syncthreads();
  if (t < 128) {
    int h = t >> 4, d = t & 15;
    int vb = 256 + h * 16 + d;
    float s = 0.f;
#pragma unroll
    for (int ki = 0; ki < 17; ki++) s += cw[h][ki] * qt[vb][ki];
    mean_ctx[(size_t)b * 128 + t] = s;
  }
}

// ---------------- K4: enhanced_x = x + mean_ctx @ M^T + b' ----------------
__global__ __launch_bounds__(256) void k4_out(
    const float* __restrict__ x, const float* __restrict__ mc,
    const float* __restrict__ M, const float* __restrict__ bf,
    float* __restrict__ out)
{
  __shared__ float ms[32][128];
  __shared__ float wt[128][65];
  const int t = threadIdx.x;
  const int b0 = blockIdx.x * 32;
  {
    int r = t >> 3, c0 = (t & 7) * 16;
    const float* s = mc + (size_t)(b0 + r) * 128 + c0;
#pragma unroll
    for (int q = 0; q < 16; q++) ms[r][c0 + q] = s[q];
  }
  const int i = t & 127, rg = t >> 7;
  const int il = t >> 1, kb = (t & 1) * 32;
  for (int oc = 0; oc < 4; oc++) {
    float acc[16];
#pragma unroll
    for (int rr = 0; rr < 16; rr++) acc[rr] = 0.f;
    for (int kc = 0; kc < 128; kc += 64) {
      __syncthreads();
      const float* wr = M + (oc * 128 + il) * 128 + kc + kb;
#pragma unroll
      for (int q = 0; q < 32; q++) wt[il][kb + q] = wr[q];
      __syncthreads();
#pragma unroll
      for (int kk = 0; kk < 64; kk++) {
        float w = wt[i][kk];
#pragma unroll
        for (int rr = 0; rr < 16; rr++) acc[rr] += w * ms[rg * 16 + rr][kc + kk];
      }
    }
    float bb = bf[oc * 128 + i];
#pragma unroll
    for (int rr = 0; rr < 16; rr++) {
      size_t idx = (size_t)(b0 + rg * 16 + rr) * 512 + oc * 128 + i;
      out[idx] = x[idx] + acc[rr] + bb;
    }
  }
}

// ---------------- host ----------------
extern "C" void kernel_launch(void* const* d_in, const int* in_sizes, int n_in,
                              void* d_out, int out_size, void* d_ws, size_t ws_size,
                              hipStream_t stream)
{
  const float* x      = (const float*)d_in[0];
  const float* af     = (const float*)d_in[1];
  const float* costs  = (const float*)d_in[2];
  const float* ue_w1  = (const float*)d_in[3];
  const float* ue_b1  = (const float*)d_in[4];
  const float* ue_w2  = (const float*)d_in[5];
  const float* ue_b2  = (const float*)d_in[6];
  const float* fi_w1  = (const float*)d_in[7];
  const float* fi_b1  = (const float*)d_in[8];
  const float* fi_w2  = (const float*)d_in[9];
  const float* fi_b2  = (const float*)d_in[10];
  const float* sd_w1  = (const float*)d_in[11];
  const float* sd_b1  = (const float*)d_in[12];
  const float* sd_w2  = (const float*)d_in[13];
  const float* sd_b2  = (const float*)d_in[14];
  const float* enc_w  = (const float*)d_in[15];
  const float* enc_b  = (const float*)d_in[16];
  const float* ipw    = (const float*)d_in[17];
  const float* ipb    = (const float*)d_in[18];
  const float* opjw   = (const float*)d_in[19];
  const float* opjb   = (const float*)d_in[20];
  const float* op_w   = (const float*)d_in[21];
  const float* op_b   = (const float*)d_in[22];

  float* out = (float*)d_out;
  float* out_enh  = out;                    // [B,512]
  float* out_unc  = out + 4194304;          // [B,1]
  float* out_fi   = out_unc + 8192;         // [B,64]
  float* out_sp   = out_fi + 524288;        // [B,64]
  float* out_mask = out_sp + 524288;        // [B,64]
  float* out_cost = out_mask + 524288;      // [B]

  char* ws = (char*)d_ws;
  __hip_bfloat16* qkv     = (__hip_bfloat16*)ws;                  // 100,663,296 B
  __hip_bfloat16* encw_bf = (__hip_bfloat16*)(ws + 100663296);    // 4,194,304 B (K0b->K2)
  float*          mc      = (float*)(ws + 100663296);             // alias: K3->K4 (4 MB)
  __hip_bfloat16* ipw_bf  = (__hip_bfloat16*)(ws + 104857600);    // 98,304 B
  float*          M       = (float*)(ws + 104955904);             // 262,144 B
  float*          bfv     = (float*)(ws + 105218048);             // 2,048 B
  int*            rows    = (int*)(ws + 105220096);               // 2,097,152 B
  int*            counts  = (int*)(ws + 107317248);               // 256 B

  hipMemsetAsync(counts, 0, 64 * sizeof(int), stream);
  k0_fuse<<<257, 256, 0, stream>>>(op_w, opjw, opjb, op_b, M, bfv);
  k0b_cvt<<<2096, 256, 0, stream>>>(enc_w, ipw, encw_bf, ipw_bf);
  k1_mlp<<<512, 256, 0, stream>>>(x, costs, ue_w1, ue_b1, ue_w2, ue_b2,
                                  fi_w1, fi_b1, fi_w2, fi_b2,
                                  sd_w1, sd_b1, sd_w2, sd_b2,
                                  out_unc, out_fi, out_sp, out_mask, out_cost,
                                  rows, counts);
  k2_mfma<<<dim3(64, 256), 256, 0, stream>>>(af, encw_bf, enc_b, ipw_bf, ipb,
                                             rows, counts, qkv);
  k3_attn<<<8192, 192, 0, stream>>>(qkv, ipb, mc);
  k4_out<<<256, 256, 0, stream>>>(x, mc, M, bfv, out_enh);
}